// Round 1
// baseline (475.749 us; speedup 1.0000x reference)
//
#include <hip/hip_runtime.h>
#include <cstdint>
#include <cstddef>

typedef _Float16 f16x8 __attribute__((ext_vector_type(8)));
typedef _Float16 f16x4 __attribute__((ext_vector_type(4)));
typedef float    f32x4 __attribute__((ext_vector_type(4)));
typedef unsigned u32;
typedef const u32 __attribute__((address_space(1)))* gas_ptr;
typedef u32 __attribute__((address_space(3)))* las_ptr;

#define MFMA16(a, b, c) __builtin_amdgcn_mfma_f32_16x16x32_f16((a), (b), (c), 0, 0, 0)

static constexpr int Bb   = 16;
static constexpr int Ss   = 1024;
static constexpr int HID  = 768;
static constexpr int Hh   = 12;
static constexpr int DH   = 64;
static constexpr int Mrows = Bb * Ss;     // 16384
static constexpr int N3    = 3 * HID;     // 2304

// ---------------- cast hs (f32 -> f16), vectorized x4 ----------------
__global__ void cast_f32_to_f16(const float* __restrict__ x, _Float16* __restrict__ y, int n4) {
    int i = blockIdx.x * 256 + threadIdx.x;
    if (i < n4) {
        float4 v = ((const float4*)x)[i];
        f16x4 o;
        o[0] = (_Float16)v.x; o[1] = (_Float16)v.y;
        o[2] = (_Float16)v.z; o[3] = (_Float16)v.w;
        ((f16x4*)y)[i] = o;
    }
}

// ---------------- pack Wq/Wk/Wv -> Wt[2304][768] f16 (B^T layout), bias concat ----------------
__global__ void pack_w(const float* __restrict__ Wq, const float* __restrict__ Wk,
                       const float* __restrict__ Wv, const float* __restrict__ bq,
                       const float* __restrict__ bk, const float* __restrict__ bv,
                       _Float16* __restrict__ Wt, float* __restrict__ bias) {
    int i = blockIdx.x * 256 + threadIdx.x;   // 0 .. 2304*768-1
    if (i < N3) {
        int wsel = i / HID, j = i - wsel * HID;
        bias[i] = (wsel == 0) ? bq[j] : (wsel == 1) ? bk[j] : bv[j];
    }
    if (i < N3 * HID) {
        int n = i / HID, k = i - n * HID;
        int sel = n / HID;          // 0,1,2
        int nn  = n - sel * HID;
        const float* W = (sel == 0) ? Wq : (sel == 1) ? Wk : Wv;
        Wt[i] = (_Float16)W[nn * HID + k];
    }
}

// ---------------- fused QKV projection GEMM (m97 structure, fp16 MFMA) ----------------
// C[M=16384, N=2304] = A[M,768] * Wt^T ; epilogue scatters into Q/K ([BH][S][64]) and VT ([BH][64][S])
__global__ __launch_bounds__(256, 2) void qkv_gemm(
    const _Float16* __restrict__ A, const _Float16* __restrict__ Bt,
    const float* __restrict__ bias,
    _Float16* __restrict__ Qo, _Float16* __restrict__ Ko, _Float16* __restrict__ VTo) {
    __shared__ _Float16 As[128 * 32];
    __shared__ _Float16 Bs[128 * 32];
    const int tid  = threadIdx.x;
    const int lane = tid & 63, wid = tid >> 6;
    const int g = lane >> 4, c = lane & 15;
    const int bm = blockIdx.x & 127, bn = blockIdx.x >> 7;  // 128 x 18 blocks
    const int m0 = bm * 128, n0 = bn * 128;
    const int wm = wid >> 1, wn = wid & 1;

    f32x4 acc[4][4] = {};

    for (int kt = 0; kt < HID; kt += 32) {
        if (kt) __syncthreads();   // protect LDS from overwrite while previous tile is read
        // stage A-tile [128][32] and B-tile [128][32]: 2x 16B chunks per thread each
#pragma unroll
        for (int i = 0; i < 2; ++i) {
            int ch  = i * 256 + wid * 64 + lane;    // chunk id 0..511
            int row = ch >> 2;
            int kh  = (ch & 3) << 3;
            __builtin_amdgcn_global_load_lds(
                (gas_ptr)(A + (size_t)(m0 + row) * HID + kt + kh),
                (las_ptr)(As + (i * 256 + wid * 64) * 8), 16, 0, 0);
            __builtin_amdgcn_global_load_lds(
                (gas_ptr)(Bt + (size_t)(n0 + row) * HID + kt + kh),
                (las_ptr)(Bs + (i * 256 + wid * 64) * 8), 16, 0, 0);
        }
        __syncthreads();

        f16x8 af[4], bf[4];
#pragma unroll
        for (int mi = 0; mi < 4; ++mi)
            af[mi] = *(const f16x8*)(As + (wm * 64 + mi * 16 + c) * 32 + g * 8);
#pragma unroll
        for (int ni = 0; ni < 4; ++ni)
            bf[ni] = *(const f16x8*)(Bs + (wn * 64 + ni * 16 + c) * 32 + g * 8);
#pragma unroll
        for (int mi = 0; mi < 4; ++mi)
#pragma unroll
            for (int ni = 0; ni < 4; ++ni)
                acc[mi][ni] = MFMA16(af[mi], bf[ni], acc[mi][ni]);
    }

    // epilogue: D[row][col]: row=(l>>4)*4+r, col=l&15 (verified C/D layout)
#pragma unroll
    for (int ni = 0; ni < 4; ++ni) {
        const int col    = n0 + wn * 64 + ni * 16 + c;
        const int which  = col / HID;           // 0=q 1=k 2=v
        const int within = col - which * HID;
        const int hh = within >> 6, d = within & 63;
        const float bias_v = bias[col];
#pragma unroll
        for (int mi = 0; mi < 4; ++mi) {
#pragma unroll
            for (int r = 0; r < 4; ++r) {
                const int rowg = m0 + wm * 64 + mi * 16 + g * 4 + r;
                const int bidx = rowg >> 10, s = rowg & 1023;
                const int bh   = bidx * Hh + hh;
                const _Float16 hv = (_Float16)(acc[mi][ni][r] + bias_v);
                if (which == 0)      Qo[((size_t)bh * Ss + s) * DH + d] = hv;
                else if (which == 1) Ko[((size_t)bh * Ss + s) * DH + d] = hv;
                else                 VTo[((size_t)bh * DH + d) * Ss + s] = hv;
            }
        }
    }
}

// ---------------- flash attention + NTK linear-attention correction ----------------
// block = 256 threads = 4 waves; each block: one (bh, 64-row q-tile); each wave: 16 q-rows.
__global__ __launch_bounds__(256, 2) void attn_kernel(
    const _Float16* __restrict__ Q, const _Float16* __restrict__ K,
    const _Float16* __restrict__ VT, const float* __restrict__ phi_k,
    const float* __restrict__ phi_kv, float* __restrict__ out) {
    __shared__ _Float16 Plds[4][16 * 64];
    __shared__ float dots[4][16];

    const int tid  = threadIdx.x;
    const int lane = tid & 63, w = tid >> 6;
    const int g = lane >> 4, c = lane & 15;
    const int bh = blockIdx.x >> 4, qt = blockIdx.x & 15;
    const int b = bh / Hh, h = bh - b * Hh;
    const size_t base = (size_t)bh * Ss * DH;

    // Q A-fragments, held in registers for the whole kernel
    const _Float16* Qp = Q + base + (size_t)(qt * 64 + w * 16 + c) * DH + g * 8;
    const f16x8 aq0 = *(const f16x8*)(Qp);
    const f16x8 aq1 = *(const f16x8*)(Qp + 32);

    float m[4]    = {-1e30f, -1e30f, -1e30f, -1e30f};
    float lsum[4] = {0.f, 0.f, 0.f, 0.f};
    f32x4 acco[4] = {};
    _Float16* Pw = &Plds[w][0];

    for (int t0 = 0; t0 < Ss; t0 += 64) {
        // ---- scores: S = Q K^T / 8 ----
        f32x4 sa[4];
#pragma unroll
        for (int nt = 0; nt < 4; ++nt) {
            const _Float16* Kp = K + base + (size_t)(t0 + nt * 16 + c) * DH + g * 8;
            f16x8 bk0 = *(const f16x8*)Kp;
            f16x8 bk1 = *(const f16x8*)(Kp + 32);
            f32x4 z = {};
            z = MFMA16(aq0, bk0, z);
            z = MFMA16(aq1, bk1, z);
            sa[nt] = z * 0.125f;
        }
        // ---- online softmax (rows = (g*4+r), cols spread over nt x 16 lanes) ----
        float alpha[4], p[4][4], part[4];
#pragma unroll
        for (int r = 0; r < 4; ++r) {
            float v = fmaxf(fmaxf(sa[0][r], sa[1][r]), fmaxf(sa[2][r], sa[3][r]));
            v = fmaxf(v, __shfl_xor(v, 1));
            v = fmaxf(v, __shfl_xor(v, 2));
            v = fmaxf(v, __shfl_xor(v, 4));
            v = fmaxf(v, __shfl_xor(v, 8));
            float mn = fmaxf(m[r], v);
            alpha[r] = __expf(m[r] - mn);
            m[r] = mn;
            part[r] = 0.f;
        }
#pragma unroll
        for (int nt = 0; nt < 4; ++nt)
#pragma unroll
            for (int r = 0; r < 4; ++r) {
                p[nt][r] = __expf(sa[nt][r] - m[r]);
                part[r] += p[nt][r];
            }
#pragma unroll
        for (int r = 0; r < 4; ++r) {
            float s = part[r];
            s += __shfl_xor(s, 1);
            s += __shfl_xor(s, 2);
            s += __shfl_xor(s, 4);
            s += __shfl_xor(s, 8);
            lsum[r] = lsum[r] * alpha[r] + s;
        }
        f32x4 av;
        av[0] = alpha[0]; av[1] = alpha[1]; av[2] = alpha[2]; av[3] = alpha[3];
#pragma unroll
        for (int nd = 0; nd < 4; ++nd) acco[nd] *= av;

        // ---- P -> LDS (XOR-swizzled to kill stride-128B bank conflicts) ----
#pragma unroll
        for (int nt = 0; nt < 4; ++nt)
#pragma unroll
            for (int r = 0; r < 4; ++r) {
                int row = g * 4 + r;
                int byteoff = row * 128 + (nt * 16 + c) * 2;
                byteoff ^= (row & 7) << 4;
                *(_Float16*)((char*)Pw + byteoff) = (_Float16)p[nt][r];
            }
        // ---- P A-fragments back from LDS ----
        f16x8 pa[2];
#pragma unroll
        for (int kk = 0; kk < 2; ++kk) {
            int byteoff = c * 128 + kk * 64 + g * 16;
            byteoff ^= (c & 7) << 4;
            pa[kk] = *(const f16x8*)((char*)Pw + byteoff);
        }
        // ---- PV ----
#pragma unroll
        for (int nd = 0; nd < 4; ++nd) {
            const _Float16* Vp = VT + base + (size_t)(nd * 16 + c) * Ss + t0 + g * 8;
            f16x8 bv0 = *(const f16x8*)Vp;
            f16x8 bv1 = *(const f16x8*)(Vp + 32);
            acco[nd] = MFMA16(pa[0], bv0, acco[nd]);
            acco[nd] = MFMA16(pa[1], bv1, acco[nd]);
        }
    }

    // ---- epilogue: NTK correction + normalize ----
    // phi_q = elu(q / 64^0.25) + 1, built from the in-register Q fragments
    float pq[16];
#pragma unroll
    for (int j = 0; j < 8; ++j) {
        float x0 = (float)aq0[j] * 0.35355339f;
        float x1 = (float)aq1[j] * 0.35355339f;
        pq[j]     = (x0 > 0.f) ? (x0 + 1.f) : __expf(x0);   // elu(x)+1
        pq[8 + j] = (x1 > 0.f) ? (x1 + 1.f) : __expf(x1);
    }
    f16x8 paq0, paq1;
#pragma unroll
    for (int j = 0; j < 8; ++j) {
        paq0[j] = (_Float16)pq[j];
        paq1[j] = (_Float16)pq[8 + j];
    }
    // dot(phi_q, |phi_k|) per row
    const float* phk = phi_k + h * DH;
    float dot = 0.f;
#pragma unroll
    for (int j = 0; j < 8; ++j) {
        dot += pq[j]     * fabsf(phk[g * 8 + j]);
        dot += pq[8 + j] * fabsf(phk[32 + g * 8 + j]);
    }
    dot += __shfl_xor(dot, 16);
    dot += __shfl_xor(dot, 32);
    dots[w][c] = dot;   // all g-lanes write identical value; benign

    // corr[row][d] = phi_q @ phi_kv[h]
    const float* pkv = phi_kv + h * DH * DH;
    f32x4 accc[4] = {};
#pragma unroll
    for (int nd = 0; nd < 4; ++nd) {
        f16x8 b0, b1;
#pragma unroll
        for (int j = 0; j < 8; ++j) {
            b0[j] = (_Float16)pkv[(g * 8 + j) * DH + nd * 16 + c];
            b1[j] = (_Float16)pkv[(32 + g * 8 + j) * DH + nd * 16 + c];
        }
        accc[nd] = MFMA16(paq0, b0, accc[nd]);
        accc[nd] = MFMA16(paq1, b1, accc[nd]);
    }

#pragma unroll
    for (int r = 0; r < 4; ++r) {
        float inv_em = __expf(-m[r]);
        float D = lsum[r] + dots[w][g * 4 + r] * inv_em;
        float invD = 1.f / D;
        int srow = qt * 64 + w * 16 + g * 4 + r;
        float* op = out + ((size_t)b * Ss + srow) * HID + h * DH + c;
#pragma unroll
        for (int nd = 0; nd < 4; ++nd)
            op[nd * 16] = (acco[nd][r] + accc[nd][r] * inv_em) * invD;
    }
}

// ---------------- launch ----------------
extern "C" void kernel_launch(void* const* d_in, const int* in_sizes, int n_in,
                              void* d_out, int out_size, void* d_ws, size_t ws_size,
                              hipStream_t stream) {
    (void)in_sizes; (void)n_in; (void)out_size;
    const float* hs   = (const float*)d_in[0];
    const float* Wq   = (const float*)d_in[1];
    const float* bq   = (const float*)d_in[2];
    const float* Wk   = (const float*)d_in[3];
    const float* bk   = (const float*)d_in[4];
    const float* Wv   = (const float*)d_in[5];
    const float* bv   = (const float*)d_in[6];
    const float* phik = (const float*)d_in[7];
    const float* phikv= (const float*)d_in[8];
    float* out = (float*)d_out;

    char* ws = (char*)d_ws;
    constexpr size_t szA   = (size_t)Mrows * HID * 2;        // 25,165,824
    constexpr size_t szWt  = (size_t)N3 * HID * 2;           //  3,538,944
    constexpr size_t szBia = (size_t)N3 * 4;                 //      9,216
    constexpr size_t szQ   = (size_t)Bb * Hh * Ss * DH * 2;  // 25,165,824
    _Float16* A16  = (_Float16*)(ws);
    _Float16* Wt   = (_Float16*)(ws + szA);
    float*    bias = (float*)(ws + szA + szWt);
    _Float16* Qb   = (_Float16*)(ws + szA + szWt + szBia);
    _Float16* Kb   = (_Float16*)(ws + szA + szWt + szBia + szQ);
    _Float16* VTb  = (_Float16*)(ws + szA + szWt + szBia + 2 * szQ);
    (void)ws_size;  // requires ~104 MB of workspace

    // 1) cast hidden_states to fp16
    cast_f32_to_f16<<<(Mrows * HID / 4 + 255) / 256, 256, 0, stream>>>(hs, A16, Mrows * HID / 4);
    // 2) pack weights (B^T layout) + bias concat
    pack_w<<<(N3 * HID + 255) / 256, 256, 0, stream>>>(Wq, Wk, Wv, bq, bk, bv, Wt, bias);
    // 3) fused QKV projection
    qkv_gemm<<<dim3((Mrows / 128) * (N3 / 128)), 256, 0, stream>>>(A16, Wt, bias, Qb, Kb, VTb);
    // 4) flash attention + NTK correction + output
    attn_kernel<<<dim3(Bb * Hh * (Ss / 64)), 256, 0, stream>>>(Qb, Kb, VTb, phik, phikv, out);
}

// Round 2
// 300.894 us; speedup vs baseline: 1.5811x; 1.5811x over previous
//
#include <hip/hip_runtime.h>
#include <cstdint>
#include <cstddef>

typedef _Float16 f16x8 __attribute__((ext_vector_type(8)));
typedef _Float16 f16x4 __attribute__((ext_vector_type(4)));
typedef float    f32x4 __attribute__((ext_vector_type(4)));
typedef unsigned u32;
typedef const u32 __attribute__((address_space(1)))* gas_ptr;
typedef u32 __attribute__((address_space(3)))* las_ptr;

#define MFMA16(a, b, c) __builtin_amdgcn_mfma_f32_16x16x32_f16((a), (b), (c), 0, 0, 0)

static constexpr int Bb   = 16;
static constexpr int Ss   = 1024;
static constexpr int HID  = 768;
static constexpr int Hh   = 12;
static constexpr int DH   = 64;
static constexpr int Mrows = Bb * Ss;     // 16384
static constexpr int N3    = 3 * HID;     // 2304

// ---------------- cast hs (f32 -> f16), vectorized x4 ----------------
__global__ void cast_f32_to_f16(const float* __restrict__ x, _Float16* __restrict__ y, int n4) {
    int i = blockIdx.x * 256 + threadIdx.x;
    if (i < n4) {
        float4 v = ((const float4*)x)[i];
        f16x4 o;
        o[0] = (_Float16)v.x; o[1] = (_Float16)v.y;
        o[2] = (_Float16)v.z; o[3] = (_Float16)v.w;
        ((f16x4*)y)[i] = o;
    }
}

// ---------------- pack Wq/Wk/Wv -> Wt[2304][768] f16 (B^T layout), bias concat ----------------
__global__ void pack_w(const float* __restrict__ Wq, const float* __restrict__ Wk,
                       const float* __restrict__ Wv, const float* __restrict__ bq,
                       const float* __restrict__ bk, const float* __restrict__ bv,
                       _Float16* __restrict__ Wt, float* __restrict__ bias) {
    int i = blockIdx.x * 256 + threadIdx.x;   // 0 .. 2304*768-1
    if (i < N3) {
        int wsel = i / HID, j = i - wsel * HID;
        bias[i] = (wsel == 0) ? bq[j] : (wsel == 1) ? bk[j] : bv[j];
    }
    if (i < N3 * HID) {
        int n = i / HID, k = i - n * HID;
        int sel = n / HID;          // 0,1,2
        int nn  = n - sel * HID;
        const float* W = (sel == 0) ? Wq : (sel == 1) ? Wk : Wv;
        Wt[i] = (_Float16)W[nn * HID + k];
    }
}

// ---------------- fused QKV projection GEMM (m97 structure, fp16 MFMA) ----------------
__global__ __launch_bounds__(256, 2) void qkv_gemm(
    const _Float16* __restrict__ A, const _Float16* __restrict__ Bt,
    const float* __restrict__ bias,
    _Float16* __restrict__ Qo, _Float16* __restrict__ Ko, _Float16* __restrict__ VTo) {
    __shared__ _Float16 As[128 * 32];
    __shared__ _Float16 Bs[128 * 32];
    const int tid  = threadIdx.x;
    const int lane = tid & 63, wid = tid >> 6;
    const int g = lane >> 4, c = lane & 15;
    const int bm = blockIdx.x & 127, bn = blockIdx.x >> 7;  // 128 x 18 blocks
    const int m0 = bm * 128, n0 = bn * 128;
    const int wm = wid >> 1, wn = wid & 1;

    f32x4 acc[4][4] = {};

    for (int kt = 0; kt < HID; kt += 32) {
        if (kt) __syncthreads();
#pragma unroll
        for (int i = 0; i < 2; ++i) {
            int ch  = i * 256 + wid * 64 + lane;    // chunk id 0..511
            int row = ch >> 2;
            int kh  = (ch & 3) << 3;
            __builtin_amdgcn_global_load_lds(
                (gas_ptr)(A + (size_t)(m0 + row) * HID + kt + kh),
                (las_ptr)(As + (i * 256 + wid * 64) * 8), 16, 0, 0);
            __builtin_amdgcn_global_load_lds(
                (gas_ptr)(Bt + (size_t)(n0 + row) * HID + kt + kh),
                (las_ptr)(Bs + (i * 256 + wid * 64) * 8), 16, 0, 0);
        }
        __syncthreads();

        f16x8 af[4], bf[4];
#pragma unroll
        for (int mi = 0; mi < 4; ++mi)
            af[mi] = *(const f16x8*)(As + (wm * 64 + mi * 16 + c) * 32 + g * 8);
#pragma unroll
        for (int ni = 0; ni < 4; ++ni)
            bf[ni] = *(const f16x8*)(Bs + (wn * 64 + ni * 16 + c) * 32 + g * 8);
#pragma unroll
        for (int mi = 0; mi < 4; ++mi)
#pragma unroll
            for (int ni = 0; ni < 4; ++ni)
                acc[mi][ni] = MFMA16(af[mi], bf[ni], acc[mi][ni]);
    }

#pragma unroll
    for (int ni = 0; ni < 4; ++ni) {
        const int col    = n0 + wn * 64 + ni * 16 + c;
        const int which  = col / HID;           // 0=q 1=k 2=v
        const int within = col - which * HID;
        const int hh = within >> 6, d = within & 63;
        const float bias_v = bias[col];
#pragma unroll
        for (int mi = 0; mi < 4; ++mi) {
#pragma unroll
            for (int r = 0; r < 4; ++r) {
                const int rowg = m0 + wm * 64 + mi * 16 + g * 4 + r;
                const int bidx = rowg >> 10, s = rowg & 1023;
                const int bh   = bidx * Hh + hh;
                const _Float16 hv = (_Float16)(acc[mi][ni][r] + bias_v);
                if (which == 0)      Qo[((size_t)bh * Ss + s) * DH + d] = hv;
                else if (which == 1) Ko[((size_t)bh * Ss + s) * DH + d] = hv;
                else                 VTo[((size_t)bh * DH + d) * Ss + s] = hv;
            }
        }
    }
}

// ---------------- flash attention v2: LDS-staged K/V (dbuf), 4 waves x 32 q-rows ----------------
// block = 256 threads = 4 waves; block handles one (bh, 128-row q-tile); wave: 32 rows (2 m-blocks).
__global__ __launch_bounds__(256) void attn_kernel(
    const _Float16* __restrict__ Q, const _Float16* __restrict__ K,
    const _Float16* __restrict__ VT, const float* __restrict__ phi_k,
    const float* __restrict__ phi_kv, float* __restrict__ out) {
    __shared__ _Float16 Kb[2][64 * 64];     // XOR-swizzled [row][d]
    __shared__ _Float16 Vb[2][64 * 64];     // XOR-swizzled [d][k-local]
    __shared__ _Float16 Plds[4][16 * 64];
    __shared__ float dots[4][2][16];

    const int tid  = threadIdx.x;
    const int lane = tid & 63, w = tid >> 6;
    const int g = lane >> 4, c = lane & 15;

    // XCD swizzle: 1536 blocks = 8 XCDs x 192; colocate same-bh blocks on one XCD
    const int wg = (blockIdx.x & 7) * 192 + (blockIdx.x >> 3);
    const int bh = wg >> 3, qt = wg & 7;
    const int b = bh / Hh, h = bh - b * Hh;
    const size_t base = (size_t)bh * Ss * DH;
    const _Float16* Kg = K + base;          // [1024][64]
    const _Float16* Vg = VT + base;         // [64][1024]

    // staging lane geometry (pre-swizzled source so linear LDS dest = swizzled layout)
    const int srow = lane >> 3;                       // row within 8-row chunk (== row&7)
    const int scol = (((lane & 7) ^ srow) << 4) >> 1; // f16 col index (bytes/2), XOR on bits 4-6

    // Q fragments in registers: rows qt*128 + w*32 + mb*16 + c
    const _Float16* Qp = Q + base + (size_t)(qt * 128 + w * 32 + c) * DH + g * 8;
    f16x8 aq[2][2];
    aq[0][0] = *(const f16x8*)(Qp);
    aq[0][1] = *(const f16x8*)(Qp + 32);
    aq[1][0] = *(const f16x8*)(Qp + 16 * DH);
    aq[1][1] = *(const f16x8*)(Qp + 16 * DH + 32);

    float m_[2][4], lsum[2][4];
    f32x4 acco[2][4] = {};
#pragma unroll
    for (int mb = 0; mb < 2; ++mb)
#pragma unroll
        for (int r = 0; r < 4; ++r) { m_[mb][r] = -1e30f; lsum[mb][r] = 0.f; }
    _Float16* Pw = &Plds[w][0];

    // stage tile t0 into buffer bf: each wave covers 16 rows (2 chunks of 8)
    auto stage = [&](int bf, int t0) {
#pragma unroll
        for (int i = 0; i < 2; ++i) {
            const int row0 = w * 16 + i * 8;
            __builtin_amdgcn_global_load_lds(
                (gas_ptr)(Kg + (size_t)(t0 + row0 + srow) * DH + scol),
                (las_ptr)(&Kb[bf][row0 * 64]), 16, 0, 0);
            __builtin_amdgcn_global_load_lds(
                (gas_ptr)(Vg + (size_t)(row0 + srow) * Ss + t0 + scol),
                (las_ptr)(&Vb[bf][row0 * 64]), 16, 0, 0);
        }
    };

    stage(0, 0);
    __syncthreads();

    for (int t0 = 0; t0 < Ss; t0 += 64) {
        const int bf = (t0 >> 6) & 1;
        if (t0 + 64 < Ss) stage(bf ^ 1, t0 + 64);

        // ---- QK^T for both m-blocks, K frags from swizzled LDS ----
        f32x4 sa[2][4];
#pragma unroll
        for (int nt = 0; nt < 4; ++nt) {
            const int row = nt * 16 + c;
            const char* kb = (const char*)&Kb[bf][0] + row * 128;
            const int sw = (c & 7) << 4;
            f16x8 bk0 = *(const f16x8*)(kb + ((g * 16) ^ sw));
            f16x8 bk1 = *(const f16x8*)(kb + ((64 + g * 16) ^ sw));
            f32x4 z0 = {}, z1 = {};
            z0 = MFMA16(aq[0][0], bk0, z0);
            z0 = MFMA16(aq[0][1], bk1, z0);
            z1 = MFMA16(aq[1][0], bk0, z1);
            z1 = MFMA16(aq[1][1], bk1, z1);
            sa[0][nt] = z0 * 0.125f;
            sa[1][nt] = z1 * 0.125f;
        }

        // ---- online softmax + P->LDS->A-frag, per m-block ----
        f16x8 pa[2][2];
#pragma unroll
        for (int mb = 0; mb < 2; ++mb) {
            float alpha[4], part[4];
#pragma unroll
            for (int r = 0; r < 4; ++r) {
                float v = fmaxf(fmaxf(sa[mb][0][r], sa[mb][1][r]),
                                fmaxf(sa[mb][2][r], sa[mb][3][r]));
                v = fmaxf(v, __shfl_xor(v, 1));
                v = fmaxf(v, __shfl_xor(v, 2));
                v = fmaxf(v, __shfl_xor(v, 4));
                v = fmaxf(v, __shfl_xor(v, 8));
                float mn = fmaxf(m_[mb][r], v);
                alpha[r] = __expf(m_[mb][r] - mn);
                m_[mb][r] = mn;
                part[r] = 0.f;
            }
#pragma unroll
            for (int nt = 0; nt < 4; ++nt)
#pragma unroll
                for (int r = 0; r < 4; ++r) {
                    float pv = __expf(sa[mb][nt][r] - m_[mb][r]);
                    part[r] += pv;
                    int row = g * 4 + r;
                    int byteoff = (row * 128 + (nt * 16 + c) * 2) ^ ((row & 7) << 4);
                    *(_Float16*)((char*)Pw + byteoff) = (_Float16)pv;
                }
#pragma unroll
            for (int r = 0; r < 4; ++r) {
                float s2 = part[r];
                s2 += __shfl_xor(s2, 1);
                s2 += __shfl_xor(s2, 2);
                s2 += __shfl_xor(s2, 4);
                s2 += __shfl_xor(s2, 8);
                lsum[mb][r] = lsum[mb][r] * alpha[r] + s2;
            }
            f32x4 av;
            av[0] = alpha[0]; av[1] = alpha[1]; av[2] = alpha[2]; av[3] = alpha[3];
#pragma unroll
            for (int nd = 0; nd < 4; ++nd) acco[mb][nd] *= av;
#pragma unroll
            for (int kk = 0; kk < 2; ++kk) {
                int byteoff = (c * 128 + kk * 64 + g * 16) ^ ((c & 7) << 4);
                pa[mb][kk] = *(const f16x8*)((char*)Pw + byteoff);
            }
        }

        // ---- PV: V frags shared across both m-blocks ----
#pragma unroll
        for (int nd = 0; nd < 4; ++nd) {
            const int row = nd * 16 + c;
            const char* vb = (const char*)&Vb[bf][0] + row * 128;
            const int sw = (c & 7) << 4;
            f16x8 bv0 = *(const f16x8*)(vb + ((g * 16) ^ sw));
            f16x8 bv1 = *(const f16x8*)(vb + ((64 + g * 16) ^ sw));
            acco[0][nd] = MFMA16(pa[0][0], bv0, acco[0][nd]);
            acco[0][nd] = MFMA16(pa[0][1], bv1, acco[0][nd]);
            acco[1][nd] = MFMA16(pa[1][0], bv0, acco[1][nd]);
            acco[1][nd] = MFMA16(pa[1][1], bv1, acco[1][nd]);
        }
        __syncthreads();
    }

    // ---- epilogue: NTK correction + normalize, per m-block ----
    const float* phk = phi_k + h * DH;
    const float* pkv = phi_kv + h * DH * DH;
#pragma unroll
    for (int mb = 0; mb < 2; ++mb) {
        float pq[16];
#pragma unroll
        for (int j = 0; j < 8; ++j) {
            float x0 = (float)aq[mb][0][j] * 0.35355339f;
            float x1 = (float)aq[mb][1][j] * 0.35355339f;
            pq[j]     = (x0 > 0.f) ? (x0 + 1.f) : __expf(x0);   // elu(x)+1
            pq[8 + j] = (x1 > 0.f) ? (x1 + 1.f) : __expf(x1);
        }
        f16x8 paq0, paq1;
#pragma unroll
        for (int j = 0; j < 8; ++j) {
            paq0[j] = (_Float16)pq[j];
            paq1[j] = (_Float16)pq[8 + j];
        }
        float dot = 0.f;
#pragma unroll
        for (int j = 0; j < 8; ++j) {
            dot += pq[j]     * fabsf(phk[g * 8 + j]);
            dot += pq[8 + j] * fabsf(phk[32 + g * 8 + j]);
        }
        dot += __shfl_xor(dot, 16);
        dot += __shfl_xor(dot, 32);
        dots[w][mb][c] = dot;

        f32x4 accc[4] = {};
#pragma unroll
        for (int nd = 0; nd < 4; ++nd) {
            f16x8 b0, b1;
#pragma unroll
            for (int j = 0; j < 8; ++j) {
                b0[j] = (_Float16)pkv[(g * 8 + j) * DH + nd * 16 + c];
                b1[j] = (_Float16)pkv[(32 + g * 8 + j) * DH + nd * 16 + c];
            }
            accc[nd] = MFMA16(paq0, b0, accc[nd]);
            accc[nd] = MFMA16(paq1, b1, accc[nd]);
        }

#pragma unroll
        for (int r = 0; r < 4; ++r) {
            float inv_em = __expf(-m_[mb][r]);
            float D = lsum[mb][r] + dots[w][mb][g * 4 + r] * inv_em;
            float invD = 1.f / D;
            int srow_o = qt * 128 + w * 32 + mb * 16 + g * 4 + r;
            float* op = out + ((size_t)b * Ss + srow_o) * HID + h * DH + c;
#pragma unroll
            for (int nd = 0; nd < 4; ++nd)
                op[nd * 16] = (acco[mb][nd][r] + accc[nd][r] * inv_em) * invD;
        }
    }
}

// ---------------- launch ----------------
extern "C" void kernel_launch(void* const* d_in, const int* in_sizes, int n_in,
                              void* d_out, int out_size, void* d_ws, size_t ws_size,
                              hipStream_t stream) {
    (void)in_sizes; (void)n_in; (void)out_size;
    const float* hs   = (const float*)d_in[0];
    const float* Wq   = (const float*)d_in[1];
    const float* bq   = (const float*)d_in[2];
    const float* Wk   = (const float*)d_in[3];
    const float* bk   = (const float*)d_in[4];
    const float* Wv   = (const float*)d_in[5];
    const float* bv   = (const float*)d_in[6];
    const float* phik = (const float*)d_in[7];
    const float* phikv= (const float*)d_in[8];
    float* out = (float*)d_out;

    char* ws = (char*)d_ws;
    constexpr size_t szA   = (size_t)Mrows * HID * 2;
    constexpr size_t szWt  = (size_t)N3 * HID * 2;
    constexpr size_t szBia = (size_t)N3 * 4;
    constexpr size_t szQ   = (size_t)Bb * Hh * Ss * DH * 2;
    _Float16* A16  = (_Float16*)(ws);
    _Float16* Wt   = (_Float16*)(ws + szA);
    float*    bias = (float*)(ws + szA + szWt);
    _Float16* Qb   = (_Float16*)(ws + szA + szWt + szBia);
    _Float16* Kb   = (_Float16*)(ws + szA + szWt + szBia + szQ);
    _Float16* VTb  = (_Float16*)(ws + szA + szWt + szBia + 2 * szQ);
    (void)ws_size;

    cast_f32_to_f16<<<(Mrows * HID / 4 + 255) / 256, 256, 0, stream>>>(hs, A16, Mrows * HID / 4);
    pack_w<<<(N3 * HID + 255) / 256, 256, 0, stream>>>(Wq, Wk, Wv, bq, bk, bv, Wt, bias);
    qkv_gemm<<<dim3((Mrows / 128) * (N3 / 128)), 256, 0, stream>>>(A16, Wt, bias, Qb, Kb, VTb);
    attn_kernel<<<dim3(Bb * Hh * (Ss / 128)), 256, 0, stream>>>(Qb, Kb, VTb, phik, phikv, out);
}

// Round 6
// 240.745 us; speedup vs baseline: 1.9761x; 1.2498x over previous
//
#include <hip/hip_runtime.h>
#include <cstdint>
#include <cstddef>

typedef _Float16 f16x8 __attribute__((ext_vector_type(8)));
typedef _Float16 f16x4 __attribute__((ext_vector_type(4)));
typedef float    f32x4 __attribute__((ext_vector_type(4)));
typedef unsigned u32;
typedef const u32 __attribute__((address_space(1)))* gas_ptr;
typedef u32 __attribute__((address_space(3)))* las_ptr;

#define MFMA16(a, b, c) __builtin_amdgcn_mfma_f32_16x16x32_f16((a), (b), (c), 0, 0, 0)

static constexpr int Bb   = 16;
static constexpr int Ss   = 1024;
static constexpr int HID  = 768;
static constexpr int Hh   = 12;
static constexpr int DH   = 64;
static constexpr int Mrows = Bb * Ss;     // 16384
static constexpr int N3    = 3 * HID;     // 2304

// ---------------- cast hs (f32 -> f16), vectorized x4 ----------------
__global__ void cast_f32_to_f16(const float* __restrict__ x, _Float16* __restrict__ y, int n4) {
    int i = blockIdx.x * 256 + threadIdx.x;
    if (i < n4) {
        float4 v = ((const float4*)x)[i];
        f16x4 o;
        o[0] = (_Float16)v.x; o[1] = (_Float16)v.y;
        o[2] = (_Float16)v.z; o[3] = (_Float16)v.w;
        ((f16x4*)y)[i] = o;
    }
}

// ---------------- pack Wq/Wk/Wv -> Wt[2304][768] f16 (B^T layout), bias concat ----------------
__global__ void pack_w(const float* __restrict__ Wq, const float* __restrict__ Wk,
                       const float* __restrict__ Wv, const float* __restrict__ bq,
                       const float* __restrict__ bk, const float* __restrict__ bv,
                       _Float16* __restrict__ Wt, float* __restrict__ bias) {
    int i = blockIdx.x * 256 + threadIdx.x;   // 0 .. 2304*768-1
    if (i < N3) {
        int wsel = i / HID, j = i - wsel * HID;
        bias[i] = (wsel == 0) ? bq[j] : (wsel == 1) ? bk[j] : bv[j];
    }
    if (i < N3 * HID) {
        int n = i / HID, k = i - n * HID;
        int sel = n / HID;          // 0,1,2
        int nn  = n - sel * HID;
        const float* W = (sel == 0) ? Wq : (sel == 1) ? Wk : Wv;
        Wt[i] = (_Float16)W[nn * HID + k];
    }
}

// ---------------- fused QKV projection GEMM (m97 structure, fp16 MFMA) ----------------
// Q output is pre-scaled by 1/8 (the 1/sqrt(DH) score scale), folded here for free.
__global__ __launch_bounds__(256, 2) void qkv_gemm(
    const _Float16* __restrict__ A, const _Float16* __restrict__ Bt,
    const float* __restrict__ bias,
    _Float16* __restrict__ Qo, _Float16* __restrict__ Ko, _Float16* __restrict__ VTo) {
    __shared__ _Float16 As[128 * 32];
    __shared__ _Float16 Bs[128 * 32];
    const int tid  = threadIdx.x;
    const int lane = tid & 63, wid = tid >> 6;
    const int g = lane >> 4, c = lane & 15;
    const int bm = blockIdx.x & 127, bn = blockIdx.x >> 7;  // 128 x 18 blocks
    const int m0 = bm * 128, n0 = bn * 128;
    const int wm = wid >> 1, wn = wid & 1;

    f32x4 acc[4][4] = {};

    for (int kt = 0; kt < HID; kt += 32) {
        if (kt) __syncthreads();
#pragma unroll
        for (int i = 0; i < 2; ++i) {
            int ch  = i * 256 + wid * 64 + lane;    // chunk id 0..511
            int row = ch >> 2;
            int kh  = (ch & 3) << 3;
            __builtin_amdgcn_global_load_lds(
                (gas_ptr)(A + (size_t)(m0 + row) * HID + kt + kh),
                (las_ptr)(As + (i * 256 + wid * 64) * 8), 16, 0, 0);
            __builtin_amdgcn_global_load_lds(
                (gas_ptr)(Bt + (size_t)(n0 + row) * HID + kt + kh),
                (las_ptr)(Bs + (i * 256 + wid * 64) * 8), 16, 0, 0);
        }
        __syncthreads();

        f16x8 af[4], bf[4];
#pragma unroll
        for (int mi = 0; mi < 4; ++mi)
            af[mi] = *(const f16x8*)(As + (wm * 64 + mi * 16 + c) * 32 + g * 8);
#pragma unroll
        for (int ni = 0; ni < 4; ++ni)
            bf[ni] = *(const f16x8*)(Bs + (wn * 64 + ni * 16 + c) * 32 + g * 8);
#pragma unroll
        for (int mi = 0; mi < 4; ++mi)
#pragma unroll
            for (int ni = 0; ni < 4; ++ni)
                acc[mi][ni] = MFMA16(af[mi], bf[ni], acc[mi][ni]);
    }

#pragma unroll
    for (int ni = 0; ni < 4; ++ni) {
        const int col    = n0 + wn * 64 + ni * 16 + c;
        const int which  = col / HID;           // 0=q 1=k 2=v
        const int within = col - which * HID;
        const int hh = within >> 6, d = within & 63;
        const float bias_v = bias[col];
        const float scl = (which == 0) ? 0.125f : 1.0f;
#pragma unroll
        for (int mi = 0; mi < 4; ++mi) {
#pragma unroll
            for (int r = 0; r < 4; ++r) {
                const int rowg = m0 + wm * 64 + mi * 16 + g * 4 + r;
                const int bidx = rowg >> 10, s = rowg & 1023;
                const int bh   = bidx * Hh + hh;
                const _Float16 hv = (_Float16)((acc[mi][ni][r] + bias_v) * scl);
                if (which == 0)      Qo[((size_t)bh * Ss + s) * DH + d] = hv;
                else if (which == 1) Ko[((size_t)bh * Ss + s) * DH + d] = hv;
                else                 VTo[((size_t)bh * DH + d) * Ss + s] = hv;
            }
        }
    }
}

// ---------------- flash attention v4: fixed-max softmax on the VERIFIED round-2 P path ----------------
// block = 256 threads = 4 waves; block: one (bh, 128-row q-tile); wave: 32 rows (2 m-blocks).
// Fixed m=0 is exact: ctx = (sum(e^s v) + phi_q phi_kv) / (sum(e^s) + phi_q|phi_k|).
__global__ __launch_bounds__(256) void attn_kernel(
    const _Float16* __restrict__ Q, const _Float16* __restrict__ K,
    const _Float16* __restrict__ VT, const float* __restrict__ phi_k,
    const float* __restrict__ phi_kv, float* __restrict__ out) {
    __shared__ _Float16 Kb[2][64 * 64];     // XOR-swizzled [row][d]
    __shared__ _Float16 Vb[2][64 * 64];     // XOR-swizzled [d][k-local]
    __shared__ _Float16 Plds[4][16 * 64];   // per-wave P, XOR-swizzled [q-local][k-local]
    __shared__ float dots[4][2][16];

    const int tid  = threadIdx.x;
    const int lane = tid & 63, w = tid >> 6;
    const int g = lane >> 4, c = lane & 15;

    // XCD swizzle: 1536 blocks = 8 XCDs x 192; colocate same-bh blocks on one XCD
    const int wg = (blockIdx.x & 7) * 192 + (blockIdx.x >> 3);
    const int bh = wg >> 3, qt = wg & 7;
    const int b = bh / Hh, h = bh - b * Hh;
    const size_t base = (size_t)bh * Ss * DH;
    const _Float16* Kg = K + base;          // [1024][64]
    const _Float16* Vg = VT + base;         // [64][1024]

    // staging lane geometry (pre-swizzled source so linear LDS dest = swizzled layout)
    const int srow = lane >> 3;                       // row within 8-row chunk (== row&7)
    const int scol = (((lane & 7) ^ srow) << 4) >> 1; // f16 col index, XOR on byte bits 4-6

    // Q fragments (pre-scaled by 1/8 at the GEMM): rows qt*128 + w*32 + mb*16 + c
    const _Float16* Qp = Q + base + (size_t)(qt * 128 + w * 32 + c) * DH + g * 8;
    f16x8 aq[2][2];
    aq[0][0] = *(const f16x8*)(Qp);
    aq[0][1] = *(const f16x8*)(Qp + 32);
    aq[1][0] = *(const f16x8*)(Qp + 16 * DH);
    aq[1][1] = *(const f16x8*)(Qp + 16 * DH + 32);

    float part[2][4] = {};
    f32x4 acco[2][4] = {};
    _Float16* Pw = &Plds[w][0];

    auto stage = [&](int bf, int t0) {
#pragma unroll
        for (int i = 0; i < 2; ++i) {
            const int row0 = w * 16 + i * 8;
            __builtin_amdgcn_global_load_lds(
                (gas_ptr)(Kg + (size_t)(t0 + row0 + srow) * DH + scol),
                (las_ptr)(&Kb[bf][row0 * 64]), 16, 0, 0);
            __builtin_amdgcn_global_load_lds(
                (gas_ptr)(Vg + (size_t)(row0 + srow) * Ss + t0 + scol),
                (las_ptr)(&Vb[bf][row0 * 64]), 16, 0, 0);
        }
    };

    stage(0, 0);
    __syncthreads();

    for (int t0 = 0; t0 < Ss; t0 += 64) {
        const int bf = (t0 >> 6) & 1;
        if (t0 + 64 < Ss) stage(bf ^ 1, t0 + 64);

        // ---- QK^T: scores come out pre-scaled (Q carries the 1/8) ----
        f32x4 z[2][4];
#pragma unroll
        for (int nt = 0; nt < 4; ++nt) {
            const int row = nt * 16 + c;
            const char* kb = (const char*)&Kb[bf][0] + row * 128;
            const int sw = (c & 7) << 4;
            f16x8 bk0 = *(const f16x8*)(kb + ((g * 16) ^ sw));
            f16x8 bk1 = *(const f16x8*)(kb + ((64 + g * 16) ^ sw));
            f32x4 z0 = {}, z1 = {};
            z0 = MFMA16(aq[0][0], bk0, z0);
            z0 = MFMA16(aq[0][1], bk1, z0);
            z1 = MFMA16(aq[1][0], bk0, z1);
            z1 = MFMA16(aq[1][1], bk1, z1);
            z[0][nt] = z0;
            z[1][nt] = z1;
        }

        // ---- P = e^s (fixed max), accumulate row-partials, P -> LDS (round-2 verified path) ----
        f16x8 pa[2][2];
#pragma unroll
        for (int mb = 0; mb < 2; ++mb) {
#pragma unroll
            for (int nt = 0; nt < 4; ++nt)
#pragma unroll
                for (int r = 0; r < 4; ++r) {
                    float pv = __expf(z[mb][nt][r]);
                    part[mb][r] += pv;
                    int row = g * 4 + r;
                    int byteoff = (row * 128 + (nt * 16 + c) * 2) ^ ((row & 7) << 4);
                    *(_Float16*)((char*)Pw + byteoff) = (_Float16)pv;
                }
#pragma unroll
            for (int kk = 0; kk < 2; ++kk) {
                int byteoff = (c * 128 + kk * 64 + g * 16) ^ ((c & 7) << 4);
                pa[mb][kk] = *(const f16x8*)((char*)Pw + byteoff);
            }
        }

        // ---- PV: V frags shared across both m-blocks ----
#pragma unroll
        for (int nd = 0; nd < 4; ++nd) {
            const int row = nd * 16 + c;
            const char* vb = (const char*)&Vb[bf][0] + row * 128;
            const int sw = (c & 7) << 4;
            f16x8 bv0 = *(const f16x8*)(vb + ((g * 16) ^ sw));
            f16x8 bv1 = *(const f16x8*)(vb + ((64 + g * 16) ^ sw));
            acco[0][nd] = MFMA16(pa[0][0], bv0, acco[0][nd]);
            acco[0][nd] = MFMA16(pa[0][1], bv1, acco[0][nd]);
            acco[1][nd] = MFMA16(pa[1][0], bv0, acco[1][nd]);
            acco[1][nd] = MFMA16(pa[1][1], bv1, acco[1][nd]);
        }
        __syncthreads();
    }

    // ---- epilogue: NTK correction + normalize ----
    const float* phk = phi_k + h * DH;
    const float* pkv = phi_kv + h * DH * DH;
#pragma unroll
    for (int mb = 0; mb < 2; ++mb) {
        // phi_q from in-register q/8: x = (q/8)*8*0.35355339 = aq * 2.82842712
        float pq[16];
#pragma unroll
        for (int j = 0; j < 8; ++j) {
            float x0 = (float)aq[mb][0][j] * 2.82842712f;
            float x1 = (float)aq[mb][1][j] * 2.82842712f;
            pq[j]     = (x0 > 0.f) ? (x0 + 1.f) : __expf(x0);   // elu(x)+1
            pq[8 + j] = (x1 > 0.f) ? (x1 + 1.f) : __expf(x1);
        }
        f16x8 paq0, paq1;
#pragma unroll
        for (int j = 0; j < 8; ++j) {
            paq0[j] = (_Float16)pq[j];
            paq1[j] = (_Float16)pq[8 + j];
        }
        float dot = 0.f;
#pragma unroll
        for (int j = 0; j < 8; ++j) {
            dot += pq[j]     * fabsf(phk[g * 8 + j]);
            dot += pq[8 + j] * fabsf(phk[32 + g * 8 + j]);
        }
        dot += __shfl_xor(dot, 16);
        dot += __shfl_xor(dot, 32);
        dots[w][mb][c] = dot;

        f32x4 accc[4] = {};
#pragma unroll
        for (int nd = 0; nd < 4; ++nd) {
            f16x8 b0, b1;
#pragma unroll
            for (int j = 0; j < 8; ++j) {
                b0[j] = (_Float16)pkv[(g * 8 + j) * DH + nd * 16 + c];
                b1[j] = (_Float16)pkv[(32 + g * 8 + j) * DH + nd * 16 + c];
            }
            accc[nd] = MFMA16(paq0, b0, accc[nd]);
            accc[nd] = MFMA16(paq1, b1, accc[nd]);
        }

        // row sums: reduce part over the 16 c-lanes (once, at the end)
        float ls[4];
#pragma unroll
        for (int r = 0; r < 4; ++r) {
            float s = part[mb][r];
            s += __shfl_xor(s, 1);
            s += __shfl_xor(s, 2);
            s += __shfl_xor(s, 4);
            s += __shfl_xor(s, 8);
            ls[r] = s;
        }

#pragma unroll
        for (int r = 0; r < 4; ++r) {
            float D = ls[r] + dots[w][mb][g * 4 + r];
            float invD = 1.f / D;
            int srow_o = qt * 128 + w * 32 + mb * 16 + g * 4 + r;
            float* op = out + ((size_t)b * Ss + srow_o) * HID + h * DH + c;
#pragma unroll
            for (int nd = 0; nd < 4; ++nd)
                op[nd * 16] = (acco[mb][nd][r] + accc[nd][r]) * invD;
        }
    }
}

// ---------------- launch ----------------
extern "C" void kernel_launch(void* const* d_in, const int* in_sizes, int n_in,
                              void* d_out, int out_size, void* d_ws, size_t ws_size,
                              hipStream_t stream) {
    (void)in_sizes; (void)n_in; (void)out_size;
    const float* hs   = (const float*)d_in[0];
    const float* Wq   = (const float*)d_in[1];
    const float* bq   = (const float*)d_in[2];
    const float* Wk   = (const float*)d_in[3];
    const float* bk   = (const float*)d_in[4];
    const float* Wv   = (const float*)d_in[5];
    const float* bv   = (const float*)d_in[6];
    const float* phik = (const float*)d_in[7];
    const float* phikv= (const float*)d_in[8];
    float* out = (float*)d_out;

    char* ws = (char*)d_ws;
    constexpr size_t szA   = (size_t)Mrows * HID * 2;
    constexpr size_t szWt  = (size_t)N3 * HID * 2;
    constexpr size_t szBia = (size_t)N3 * 4;
    constexpr size_t szQ   = (size_t)Bb * Hh * Ss * DH * 2;
    _Float16* A16  = (_Float16*)(ws);
    _Float16* Wt   = (_Float16*)(ws + szA);
    float*    bias = (float*)(ws + szA + szWt);
    _Float16* Qb   = (_Float16*)(ws + szA + szWt + szBia);
    _Float16* Kb   = (_Float16*)(ws + szA + szWt + szBia + szQ);
    _Float16* VTb  = (_Float16*)(ws + szA + szWt + szBia + 2 * szQ);
    (void)ws_size;

    cast_f32_to_f16<<<(Mrows * HID / 4 + 255) / 256, 256, 0, stream>>>(hs, A16, Mrows * HID / 4);
    pack_w<<<(N3 * HID + 255) / 256, 256, 0, stream>>>(Wq, Wk, Wv, bq, bk, bv, Wt, bias);
    qkv_gemm<<<dim3((Mrows / 128) * (N3 / 128)), 256, 0, stream>>>(A16, Wt, bias, Qb, Kb, VTb);
    attn_kernel<<<dim3(Bb * Hh * (Ss / 128)), 256, 0, stream>>>(Qb, Kb, VTb, phik, phikv, out);
}

// Round 7
// 204.004 us; speedup vs baseline: 2.3321x; 1.1801x over previous
//
#include <hip/hip_runtime.h>
#include <cstdint>
#include <cstddef>

typedef _Float16 f16x8 __attribute__((ext_vector_type(8)));
typedef _Float16 f16x4 __attribute__((ext_vector_type(4)));
typedef float    f32x4 __attribute__((ext_vector_type(4)));
typedef unsigned u32;
typedef u32      u32x4 __attribute__((ext_vector_type(4)));
typedef const u32 __attribute__((address_space(1)))* gas_ptr;
typedef u32 __attribute__((address_space(3)))* las_ptr;

#define MFMA16(a, b, c) __builtin_amdgcn_mfma_f32_16x16x32_f16((a), (b), (c), 0, 0, 0)

static constexpr int Bb   = 16;
static constexpr int Ss   = 1024;
static constexpr int HID  = 768;
static constexpr int Hh   = 12;
static constexpr int DH   = 64;
static constexpr int Mrows = Bb * Ss;     // 16384
static constexpr int N3    = 3 * HID;     // 2304

// ---------------- cast hs (f32 -> f16), vectorized x4 ----------------
__global__ void cast_f32_to_f16(const float* __restrict__ x, _Float16* __restrict__ y, int n4) {
    int i = blockIdx.x * 256 + threadIdx.x;
    if (i < n4) {
        float4 v = ((const float4*)x)[i];
        f16x4 o;
        o[0] = (_Float16)v.x; o[1] = (_Float16)v.y;
        o[2] = (_Float16)v.z; o[3] = (_Float16)v.w;
        ((f16x4*)y)[i] = o;
    }
}

// ---------------- pack Wq/Wk/Wv -> Wt[2304][768] f16 (B^T layout), bias concat ----------------
__global__ void pack_w(const float* __restrict__ Wq, const float* __restrict__ Wk,
                       const float* __restrict__ Wv, const float* __restrict__ bq,
                       const float* __restrict__ bk, const float* __restrict__ bv,
                       _Float16* __restrict__ Wt, float* __restrict__ bias) {
    int i = blockIdx.x * 256 + threadIdx.x;   // 0 .. 2304*768-1
    if (i < N3) {
        int wsel = i / HID, j = i - wsel * HID;
        bias[i] = (wsel == 0) ? bq[j] : (wsel == 1) ? bk[j] : bv[j];
    }
    if (i < N3 * HID) {
        int n = i / HID, k = i - n * HID;
        int sel = n / HID;          // 0,1,2
        int nn  = n - sel * HID;
        const float* W = (sel == 0) ? Wq : (sel == 1) ? Wk : Wv;
        Wt[i] = (_Float16)W[nn * HID + k];
    }
}

// ---------------- fused QKV projection GEMM (m97 structure, fp16 MFMA) ----------------
// Q output is pre-scaled by 1/8 (the 1/sqrt(DH) score scale), folded here for free.
__global__ __launch_bounds__(256, 2) void qkv_gemm(
    const _Float16* __restrict__ A, const _Float16* __restrict__ Bt,
    const float* __restrict__ bias,
    _Float16* __restrict__ Qo, _Float16* __restrict__ Ko, _Float16* __restrict__ VTo) {
    __shared__ _Float16 As[128 * 32];
    __shared__ _Float16 Bs[128 * 32];
    const int tid  = threadIdx.x;
    const int lane = tid & 63, wid = tid >> 6;
    const int g = lane >> 4, c = lane & 15;
    const int bm = blockIdx.x & 127, bn = blockIdx.x >> 7;  // 128 x 18 blocks
    const int m0 = bm * 128, n0 = bn * 128;
    const int wm = wid >> 1, wn = wid & 1;

    f32x4 acc[4][4] = {};

    for (int kt = 0; kt < HID; kt += 32) {
        if (kt) __syncthreads();
#pragma unroll
        for (int i = 0; i < 2; ++i) {
            int ch  = i * 256 + wid * 64 + lane;    // chunk id 0..511
            int row = ch >> 2;
            int kh  = (ch & 3) << 3;
            __builtin_amdgcn_global_load_lds(
                (gas_ptr)(A + (size_t)(m0 + row) * HID + kt + kh),
                (las_ptr)(As + (i * 256 + wid * 64) * 8), 16, 0, 0);
            __builtin_amdgcn_global_load_lds(
                (gas_ptr)(Bt + (size_t)(n0 + row) * HID + kt + kh),
                (las_ptr)(Bs + (i * 256 + wid * 64) * 8), 16, 0, 0);
        }
        __syncthreads();

        f16x8 af[4], bf[4];
#pragma unroll
        for (int mi = 0; mi < 4; ++mi)
            af[mi] = *(const f16x8*)(As + (wm * 64 + mi * 16 + c) * 32 + g * 8);
#pragma unroll
        for (int ni = 0; ni < 4; ++ni)
            bf[ni] = *(const f16x8*)(Bs + (wn * 64 + ni * 16 + c) * 32 + g * 8);
#pragma unroll
        for (int mi = 0; mi < 4; ++mi)
#pragma unroll
            for (int ni = 0; ni < 4; ++ni)
                acc[mi][ni] = MFMA16(af[mi], bf[ni], acc[mi][ni]);
    }

#pragma unroll
    for (int ni = 0; ni < 4; ++ni) {
        const int col    = n0 + wn * 64 + ni * 16 + c;
        const int which  = col / HID;           // 0=q 1=k 2=v
        const int within = col - which * HID;
        const int hh = within >> 6, d = within & 63;
        const float bias_v = bias[col];
        const float scl = (which == 0) ? 0.125f : 1.0f;
#pragma unroll
        for (int mi = 0; mi < 4; ++mi) {
            const int rowg0 = m0 + wm * 64 + mi * 16 + g * 4;   // 4-aligned; r-quad same batch
            const int bidx = rowg0 >> 10, s0 = rowg0 & 1023;
            const int bh   = bidx * Hh + hh;
            f16x4 hv4;
#pragma unroll
            for (int r = 0; r < 4; ++r)
                hv4[r] = (_Float16)((acc[mi][ni][r] + bias_v) * scl);
            if (which == 2) {
                // V^T: 4 consecutive s -> one 8B store
                *(uint2*)(VTo + ((size_t)bh * DH + d) * Ss + s0) = __builtin_bit_cast(uint2, hv4);
            } else if (which == 0) {
#pragma unroll
                for (int r = 0; r < 4; ++r)
                    Qo[((size_t)bh * Ss + s0 + r) * DH + d] = hv4[r];
            } else {
#pragma unroll
                for (int r = 0; r < 4; ++r)
                    Ko[((size_t)bh * Ss + s0 + r) * DH + d] = hv4[r];
            }
        }
    }
}

// ---------------- flash attention v5: swapped QK^T, P stays in registers ----------------
// block = 256 threads = 4 waves; block: one (bh, 128-row q-tile); wave: 32 q (2 mb x 16).
// Swapped MFMA: z = MFMA(K_frag, Q_frag) -> S[k=16nt+4g+r][q=c] per lane.
// PV consumes P directly from registers with permuted k-map
//   sigma(kk,g,j) = 32kk + 16(j>>2) + 4g + (j&3), applied identically to the V fragments.
// Fixed m=0 softmax is exact: ctx = (sum(e^s v) + phi_q phi_kv) / (sum(e^s) + phi_q|phi_k|).
__global__ __launch_bounds__(256) void attn_kernel(
    const _Float16* __restrict__ Q, const _Float16* __restrict__ K,
    const _Float16* __restrict__ VT, const float* __restrict__ phi_k,
    const float* __restrict__ phi_kv, float* __restrict__ out) {
    __shared__ _Float16 Kb[2][64 * 64];     // XOR-swizzled [key][dh]
    __shared__ _Float16 Vb[2][64 * 64];     // XOR-swizzled [d][k-local]

    const int tid  = threadIdx.x;
    const int lane = tid & 63, w = tid >> 6;
    const int g = lane >> 4, c = lane & 15;

    // XCD swizzle: 1536 blocks = 8 XCDs x 192; colocate same-bh blocks on one XCD
    const int wg = (blockIdx.x & 7) * 192 + (blockIdx.x >> 3);
    const int bh = wg >> 3, qt = wg & 7;
    const int b = bh / Hh, h = bh - b * Hh;
    const size_t base = (size_t)bh * Ss * DH;
    const _Float16* Kg = K + base;          // [1024][64]
    const _Float16* Vg = VT + base;         // [64][1024]

    // staging lane geometry (pre-swizzled source so linear LDS dest = swizzled layout)
    const int srow = lane >> 3;                       // row within 8-row chunk (== row&7)
    const int scol = (((lane & 7) ^ srow) << 4) >> 1; // f16 col index, XOR on byte bits 4-6
    const int sw = (c & 7) << 4;

    // Q fragments (pre-scaled by 1/8 at the GEMM): rows qt*128 + w*32 + mb*16 + c
    const _Float16* Qp = Q + base + (size_t)(qt * 128 + w * 32 + c) * DH + g * 8;
    f16x8 aq[2][2];
    aq[0][0] = *(const f16x8*)(Qp);
    aq[0][1] = *(const f16x8*)(Qp + 32);
    aq[1][0] = *(const f16x8*)(Qp + 16 * DH);
    aq[1][1] = *(const f16x8*)(Qp + 16 * DH + 32);

    float part[2] = {0.f, 0.f};     // per-lane partial of sum(e^s) over this lane's k-slots
    f32x4 acco[2][4] = {};          // ctx^T: [mb][nd], lane holds q=c, d=nd*16+4g+r

    auto stage = [&](int bf, int t0) {
#pragma unroll
        for (int i = 0; i < 2; ++i) {
            const int row0 = w * 16 + i * 8;
            __builtin_amdgcn_global_load_lds(
                (gas_ptr)(Kg + (size_t)(t0 + row0 + srow) * DH + scol),
                (las_ptr)(&Kb[bf][row0 * 64]), 16, 0, 0);
            __builtin_amdgcn_global_load_lds(
                (gas_ptr)(Vg + (size_t)(row0 + srow) * Ss + t0 + scol),
                (las_ptr)(&Vb[bf][row0 * 64]), 16, 0, 0);
        }
    };

    stage(0, 0);
    __syncthreads();

    for (int t0 = 0; t0 < Ss; t0 += 64) {
        const int bf = (t0 >> 6) & 1;
        if (t0 + 64 < Ss) stage(bf ^ 1, t0 + 64);

        // ---- swapped QK^T: z[mb][nt] = S[k=16nt+4g+r][q=mb*16+c], pre-scaled ----
        f32x4 z[2][4];
#pragma unroll
        for (int nt = 0; nt < 4; ++nt) {
            const char* kb = (const char*)&Kb[bf][0] + (nt * 16 + c) * 128;
            f16x8 bk0 = *(const f16x8*)(kb + ((g * 16) ^ sw));
            f16x8 bk1 = *(const f16x8*)(kb + ((64 + g * 16) ^ sw));
            f32x4 z0 = {}, z1 = {};
            z0 = MFMA16(bk0, aq[0][0], z0);
            z0 = MFMA16(bk1, aq[0][1], z0);
            z1 = MFMA16(bk0, aq[1][0], z1);
            z1 = MFMA16(bk1, aq[1][1], z1);
            z[0][nt] = z0;
            z[1][nt] = z1;
        }

        // ---- P = e^s in registers, packed as PV B-fragments (k-map sigma) ----
        f16x8 pb[2][2];
#pragma unroll
        for (int mb = 0; mb < 2; ++mb) {
#pragma unroll
            for (int kk = 0; kk < 2; ++kk) {
                float e0 = __expf(z[mb][2 * kk][0]);
                float e1 = __expf(z[mb][2 * kk][1]);
                float e2 = __expf(z[mb][2 * kk][2]);
                float e3 = __expf(z[mb][2 * kk][3]);
                float e4 = __expf(z[mb][2 * kk + 1][0]);
                float e5 = __expf(z[mb][2 * kk + 1][1]);
                float e6 = __expf(z[mb][2 * kk + 1][2]);
                float e7 = __expf(z[mb][2 * kk + 1][3]);
                part[mb] += (e0 + e1 + e2 + e3) + (e4 + e5 + e6 + e7);
                u32x4 pk;
                pk[0] = __builtin_bit_cast(u32, __builtin_amdgcn_cvt_pkrtz(e0, e1));
                pk[1] = __builtin_bit_cast(u32, __builtin_amdgcn_cvt_pkrtz(e2, e3));
                pk[2] = __builtin_bit_cast(u32, __builtin_amdgcn_cvt_pkrtz(e4, e5));
                pk[3] = __builtin_bit_cast(u32, __builtin_amdgcn_cvt_pkrtz(e6, e7));
                pb[mb][kk] = __builtin_bit_cast(f16x8, pk);
            }
        }

        // ---- PV: ctx^T += V^T-frag x P-frag; V read with the same sigma k-map ----
#pragma unroll
        for (int nd = 0; nd < 4; ++nd) {
            const char* vb = (const char*)&Vb[bf][0] + (nd * 16 + c) * 128;
#pragma unroll
            for (int kk = 0; kk < 2; ++kk) {
                f16x4 vlo = *(const f16x4*)(vb + ((kk * 64 + 8 * g) ^ sw));
                f16x4 vhi = *(const f16x4*)(vb + ((kk * 64 + 32 + 8 * g) ^ sw));
                f16x8 va = __builtin_shufflevector(vlo, vhi, 0, 1, 2, 3, 4, 5, 6, 7);
                acco[0][nd] = MFMA16(va, pb[0][kk], acco[0][nd]);
                acco[1][nd] = MFMA16(va, pb[1][kk], acco[1][nd]);
            }
        }
        __syncthreads();
    }

    // ---- epilogue: phi_q (sigma-ordered Q reload), normalizer, NTK correction ----
    const float* phk = phi_k + h * DH;
    const float* pkv = phi_kv + h * DH * DH;

    f16x8 pq2[2][2];     // phi_q packed with sigma k-map, per mb
    float invD[2];
#pragma unroll
    for (int mb = 0; mb < 2; ++mb) {
        const _Float16* Qr = Q + base + (size_t)(qt * 128 + w * 32 + mb * 16 + c) * DH;
        float dot = 0.f;
#pragma unroll
        for (int kk = 0; kk < 2; ++kk) {
            f16x4 qa = *(const f16x4*)(Qr + kk * 32 + 4 * g);
            f16x4 qb = *(const f16x4*)(Qr + kk * 32 + 16 + 4 * g);
            float4 fka = *(const float4*)(phk + kk * 32 + 4 * g);
            float4 fkb = *(const float4*)(phk + kk * 32 + 16 + 4 * g);
            const float fa[4] = {fka.x, fka.y, fka.z, fka.w};
            const float fb[4] = {fkb.x, fkb.y, fkb.z, fkb.w};
            f16x8 pq;
#pragma unroll
            for (int j = 0; j < 4; ++j) {
                float x0 = (float)qa[j] * 2.82842712f;    // q / 64^0.25
                float x1 = (float)qb[j] * 2.82842712f;
                float p0 = (x0 > 0.f) ? (x0 + 1.f) : __expf(x0);
                float p1 = (x1 > 0.f) ? (x1 + 1.f) : __expf(x1);
                dot += p0 * fabsf(fa[j]) + p1 * fabsf(fb[j]);
                pq[j]     = (_Float16)p0;
                pq[4 + j] = (_Float16)p1;
            }
            pq2[mb][kk] = pq;
        }
        dot += __shfl_xor(dot, 16);
        dot += __shfl_xor(dot, 32);
        float s = part[mb];
        s += __shfl_xor(s, 16);
        s += __shfl_xor(s, 32);
        invD[mb] = 1.f / (s + dot);
    }

    // correction MFMA (A = phi_kv^T with sigma k-map, shared across mb) + output
#pragma unroll
    for (int nd = 0; nd < 4; ++nd) {
        f16x8 fa[2];
#pragma unroll
        for (int kk = 0; kk < 2; ++kk) {
            f16x8 t;
#pragma unroll
            for (int j = 0; j < 8; ++j) {
                int dh = kk * 32 + 16 * (j >> 2) + 4 * g + (j & 3);
                t[j] = (_Float16)pkv[dh * DH + nd * 16 + c];
            }
            fa[kk] = t;
        }
#pragma unroll
        for (int mb = 0; mb < 2; ++mb) {
            f32x4 cc = {};
            cc = MFMA16(fa[0], pq2[mb][0], cc);
            cc = MFMA16(fa[1], pq2[mb][1], cc);
            f32x4 o = (acco[mb][nd] + cc) * invD[mb];
            const int srow_o = qt * 128 + w * 32 + mb * 16 + c;
            float* op = out + ((size_t)b * Ss + srow_o) * HID + h * DH + nd * 16 + 4 * g;
            *(f32x4*)op = o;
        }
    }
}

// ---------------- launch ----------------
extern "C" void kernel_launch(void* const* d_in, const int* in_sizes, int n_in,
                              void* d_out, int out_size, void* d_ws, size_t ws_size,
                              hipStream_t stream) {
    (void)in_sizes; (void)n_in; (void)out_size;
    const float* hs   = (const float*)d_in[0];
    const float* Wq   = (const float*)d_in[1];
    const float* bq   = (const float*)d_in[2];
    const float* Wk   = (const float*)d_in[3];
    const float* bk   = (const float*)d_in[4];
    const float* Wv   = (const float*)d_in[5];
    const float* bv   = (const float*)d_in[6];
    const float* phik = (const float*)d_in[7];
    const float* phikv= (const float*)d_in[8];
    float* out = (float*)d_out;

    char* ws = (char*)d_ws;
    constexpr size_t szA   = (size_t)Mrows * HID * 2;
    constexpr size_t szWt  = (size_t)N3 * HID * 2;
    constexpr size_t szBia = (size_t)N3 * 4;
    constexpr size_t szQ   = (size_t)Bb * Hh * Ss * DH * 2;
    _Float16* A16  = (_Float16*)(ws);
    _Float16* Wt   = (_Float16*)(ws + szA);
    float*    bias = (float*)(ws + szA + szWt);
    _Float16* Qb   = (_Float16*)(ws + szA + szWt + szBia);
    _Float16* Kb   = (_Float16*)(ws + szA + szWt + szBia + szQ);
    _Float16* VTb  = (_Float16*)(ws + szA + szWt + szBia + 2 * szQ);
    (void)ws_size;

    cast_f32_to_f16<<<(Mrows * HID / 4 + 255) / 256, 256, 0, stream>>>(hs, A16, Mrows * HID / 4);
    pack_w<<<(N3 * HID + 255) / 256, 256, 0, stream>>>(Wq, Wk, Wv, bq, bk, bv, Wt, bias);
    qkv_gemm<<<dim3((Mrows / 128) * (N3 / 128)), 256, 0, stream>>>(A16, Wt, bias, Qb, Kb, VTb);
    attn_kernel<<<dim3(Bb * Hh * (Ss / 128)), 256, 0, stream>>>(Qb, Kb, VTb, phik, phikv, out);
}